// Round 6
// baseline (538.094 us; speedup 1.0000x reference)
//
#include <hip/hip_runtime.h>

#define NN 50000
#define NE 800000
#define NNP 50176  // 196*256

typedef __attribute__((ext_vector_type(4))) float f32x4;
typedef __bf16 bf16x8 __attribute__((ext_vector_type(8)));

__device__ __forceinline__ float bfu2f(unsigned short u) {
  return __uint_as_float(((unsigned)u) << 16);
}
__device__ __forceinline__ unsigned short f2bf(float f) {
  unsigned u = __float_as_uint(f);
  u += 0x7fffu + ((u >> 16) & 1u);
  return (unsigned short)(u >> 16);
}

// ---------------- weight prep: W[K][N] fp32 -> WT[N][K] bf16 (run once per launch)
__global__ __launch_bounds__(256) void transpose_w(
    const float* __restrict__ W, unsigned short* __restrict__ WT, int K, int N) {
  __shared__ unsigned short T[32 * 40];
  const int t = threadIdx.x;
  const int k0 = blockIdx.x * 32, n0 = blockIdx.y * 32;
  const int kk = t >> 3, nn = (t & 7) * 4;
  f32x4 v = *(const f32x4*)(W + (k0 + kk) * N + n0 + nn);
#pragma unroll
  for (int i = 0; i < 4; i++) T[(nn + i) * 40 + kk] = f2bf(v[i]);
  __syncthreads();
  const int nn2 = t >> 3, kk2 = (t & 7) * 4;
  unsigned short o[4];
#pragma unroll
  for (int i = 0; i < 4; i++) o[i] = T[nn2 * 40 + kk2 + i];
  *(uint2*)(WT + (n0 + nn2) * K + k0 + kk2) = *(const uint2*)o;
}

// ---------------- count: rank[e] = old cnt[row]++  (the only atomic pass)
__global__ __launch_bounds__(256) void count_kernel(
    const int* __restrict__ ei, int* __restrict__ cnt, int* __restrict__ rank) {
  const int e = blockIdx.x * 256 + threadIdx.x;
  if (e >= NE) return;
  rank[e] = atomicAdd(&cnt[ei[e]], 1);
}

// ---------------- CSR build: hierarchical exclusive scan of cnt
__global__ __launch_bounds__(256) void scan1_kernel(const int* __restrict__ cnt,
                                                    int* __restrict__ blockSum) {
  __shared__ int sd[256];
  const int t = threadIdx.x;
  sd[t] = cnt[blockIdx.x * 256 + t];
  __syncthreads();
  for (int off = 128; off > 0; off >>= 1) {
    if (t < off) sd[t] += sd[t + off];
    __syncthreads();
  }
  if (t == 0) blockSum[blockIdx.x] = sd[0];
}

__global__ __launch_bounds__(256) void scan2_kernel(int* __restrict__ blockSum) {
  __shared__ int sd[256];
  const int t = threadIdx.x;
  int v = (t < 196) ? blockSum[t] : 0;
  sd[t] = v;
  __syncthreads();
  for (int off = 1; off < 256; off <<= 1) {
    int y = (t >= off) ? sd[t - off] : 0;
    __syncthreads();
    sd[t] += y;
    __syncthreads();
  }
  int ex = (t == 0) ? 0 : sd[t - 1];
  __syncthreads();
  if (t < 196) blockSum[t] = ex;
}

__global__ __launch_bounds__(256) void scan3_kernel(
    const int* __restrict__ cnt, const int* __restrict__ blockSum,
    int* __restrict__ start) {
  __shared__ int sd[256];
  const int t = threadIdx.x;
  const int row = blockIdx.x * 256 + t;
  const int c = cnt[row];
  sd[t] = c;
  __syncthreads();
  for (int off = 1; off < 256; off <<= 1) {
    int y = (t >= off) ? sd[t - off] : 0;
    __syncthreads();
    sd[t] += y;
    __syncthreads();
  }
  start[row] = blockSum[blockIdx.x] + sd[t] - c;  // exclusive
}

// ---------------- fused edge MLP + CSR fill: colw[start[row]+rank[e]] = {col, softplus(MLP(ea))}
// 2 edges/thread so each LDS weight broadcast serves both. No atomics.
__device__ __forceinline__ float rdot(f32x4 h, f32x4 w) {
  float s = fmaxf(h[0], 0.0f) * w[0];
  s = fmaf(fmaxf(h[1], 0.0f), w[1], s);
  s = fmaf(fmaxf(h[2], 0.0f), w[2], s);
  s = fmaf(fmaxf(h[3], 0.0f), w[3], s);
  return s;
}

__global__ __launch_bounds__(256) void mlp_fill_kernel(
    const float* __restrict__ ea,
    const float* __restrict__ Wm1, const float* __restrict__ bm1,
    const float* __restrict__ Wm2, const float* __restrict__ bm2,
    const int* __restrict__ ei, const int* __restrict__ start,
    const int* __restrict__ rank, uint2* __restrict__ colw) {
  __shared__ __align__(16) float w1[512];
  __shared__ __align__(16) float b1[32];
  __shared__ __align__(16) float w2[32];
  __shared__ float b2s[1];
  const int t = threadIdx.x;
  w1[t] = Wm1[t];
  w1[t + 256] = Wm1[t + 256];
  if (t < 32) { b1[t] = bm1[t]; w2[t] = Wm2[t]; }
  if (t == 0) b2s[0] = bm2[0];
  __syncthreads();
  const int e0 = blockIdx.x * 256 + t;
  if (e0 >= NE / 2) return;
  const int e1 = e0 + NE / 2;
  f32x4 r0 = *(const f32x4*)(ea + e0 * 16);
  f32x4 r1 = *(const f32x4*)(ea + e0 * 16 + 4);
  f32x4 r2 = *(const f32x4*)(ea + e0 * 16 + 8);
  f32x4 r3 = *(const f32x4*)(ea + e0 * 16 + 12);
  f32x4 s0 = *(const f32x4*)(ea + e1 * 16);
  f32x4 s1 = *(const f32x4*)(ea + e1 * 16 + 4);
  f32x4 s2 = *(const f32x4*)(ea + e1 * 16 + 8);
  f32x4 s3 = *(const f32x4*)(ea + e1 * 16 + 12);
  const f32x4* bv = (const f32x4*)b1;
  f32x4 h0 = bv[0], h1 = bv[1], h2 = bv[2], h3 = bv[3];
  f32x4 h4 = bv[4], h5 = bv[5], h6 = bv[6], h7 = bv[7];
  f32x4 g0 = h0, g1 = h1, g2 = h2, g3 = h3;
  f32x4 g4 = h4, g5 = h5, g6 = h6, g7 = h7;
  const f32x4* wv = (const f32x4*)w1;
#define ROW(a_, b_, base)                                        \
  {                                                              \
    f32x4 w_;                                                    \
    w_ = wv[(base) + 0]; h0 += w_ * (a_); g0 += w_ * (b_);       \
    w_ = wv[(base) + 1]; h1 += w_ * (a_); g1 += w_ * (b_);       \
    w_ = wv[(base) + 2]; h2 += w_ * (a_); g2 += w_ * (b_);       \
    w_ = wv[(base) + 3]; h3 += w_ * (a_); g3 += w_ * (b_);       \
    w_ = wv[(base) + 4]; h4 += w_ * (a_); g4 += w_ * (b_);       \
    w_ = wv[(base) + 5]; h5 += w_ * (a_); g5 += w_ * (b_);       \
    w_ = wv[(base) + 6]; h6 += w_ * (a_); g6 += w_ * (b_);       \
    w_ = wv[(base) + 7]; h7 += w_ * (a_); g7 += w_ * (b_);       \
  }
  ROW(r0[0], s0[0], 0)  ROW(r0[1], s0[1], 8)  ROW(r0[2], s0[2], 16)  ROW(r0[3], s0[3], 24)
  ROW(r1[0], s1[0], 32) ROW(r1[1], s1[1], 40) ROW(r1[2], s1[2], 48)  ROW(r1[3], s1[3], 56)
  ROW(r2[0], s2[0], 64) ROW(r2[1], s2[1], 72) ROW(r2[2], s2[2], 80)  ROW(r2[3], s2[3], 88)
  ROW(r3[0], s3[0], 96) ROW(r3[1], s3[1], 104) ROW(r3[2], s3[2], 112) ROW(r3[3], s3[3], 120)
#undef ROW
  const f32x4* w2v = (const f32x4*)w2;
  float u = b2s[0];
  u += rdot(h0, w2v[0]) + rdot(h1, w2v[1]) + rdot(h2, w2v[2]) + rdot(h3, w2v[3]);
  u += rdot(h4, w2v[4]) + rdot(h5, w2v[5]) + rdot(h6, w2v[6]) + rdot(h7, w2v[7]);
  float v = b2s[0];
  v += rdot(g0, w2v[0]) + rdot(g1, w2v[1]) + rdot(g2, w2v[2]) + rdot(g3, w2v[3]);
  v += rdot(g4, w2v[4]) + rdot(g5, w2v[5]) + rdot(g6, w2v[6]) + rdot(g7, w2v[7]);
  const float sp0 = (u > 0.0f) ? (u + log1pf(expf(-u))) : log1pf(expf(u));
  const float sp1 = (v > 0.0f) ? (v + log1pf(expf(-v))) : log1pf(expf(v));
  const int row0 = ei[e0], row1 = ei[e1];
  const int col0 = ei[NE + e0], col1 = ei[NE + e1];
  uint2 p0, p1;
  p0.x = (unsigned)col0; p0.y = __float_as_uint(sp0);
  p1.x = (unsigned)col1; p1.y = __float_as_uint(sp1);
  colw[start[row0] + rank[e0]] = p0;
  colw[start[row1] + rank[e1]] = p1;
}

// ---------------- transform GEMM (128x128 tile): xm = mix(mask, relu(x@Wt1+bt1), relu(x@Wt0+bt0))
__global__ __launch_bounds__(256, 2) void gemm_transform(
    const float* __restrict__ X,
    const unsigned short* __restrict__ WT1, const unsigned short* __restrict__ WT0,
    const float* __restrict__ bias1, const float* __restrict__ bias0,
    const int* __restrict__ mask, unsigned short* __restrict__ xmb) {
  __shared__ __align__(16) unsigned short As[128 * 40];
  __shared__ __align__(16) unsigned short Bs1[128 * 40];
  __shared__ __align__(16) unsigned short Bs0[128 * 40];
  const int t = threadIdx.x;
  const int col0 = blockIdx.x * 128, row0 = blockIdx.y * 128;
  const int wv = t >> 6, lane = t & 63, m = lane & 15, q = lane >> 4;
  const int hr = t >> 1, hc = t & 1;  // staging: row/n index 0..127, k-half 0/1
  f32x4 acc1[2][8], acc0[2][8];
#pragma unroll
  for (int rf = 0; rf < 2; rf++)
#pragma unroll
    for (int nt = 0; nt < 8; nt++) { acc1[rf][nt] = (f32x4)(0.0f); acc0[rf][nt] = (f32x4)(0.0f); }
  const int gr = row0 + hr;
  for (int k0 = 0; k0 < 256; k0 += 32) {
    unsigned short av[16];
    if (gr < NN) {
      const float* xp = X + gr * 256 + k0 + hc * 16;
      f32x4 x0 = *(const f32x4*)(xp);
      f32x4 x1 = *(const f32x4*)(xp + 4);
      f32x4 x2 = *(const f32x4*)(xp + 8);
      f32x4 x3 = *(const f32x4*)(xp + 12);
#pragma unroll
      for (int i = 0; i < 4; i++) {
        av[i] = f2bf(x0[i]); av[4 + i] = f2bf(x1[i]);
        av[8 + i] = f2bf(x2[i]); av[12 + i] = f2bf(x3[i]);
      }
    } else {
#pragma unroll
      for (int i = 0; i < 16; i++) av[i] = 0;
    }
    *(uint4*)&As[hr * 40 + hc * 16] = ((const uint4*)av)[0];
    *(uint4*)&As[hr * 40 + hc * 16 + 8] = ((const uint4*)av)[1];
    const unsigned short* w1p = WT1 + (col0 + hr) * 256 + k0 + hc * 16;
    const unsigned short* w0p = WT0 + (col0 + hr) * 256 + k0 + hc * 16;
    uint4 b1a = *(const uint4*)w1p;
    uint4 b1b = *(const uint4*)(w1p + 8);
    uint4 b0a = *(const uint4*)w0p;
    uint4 b0b = *(const uint4*)(w0p + 8);
    *(uint4*)&Bs1[hr * 40 + hc * 16] = b1a;
    *(uint4*)&Bs1[hr * 40 + hc * 16 + 8] = b1b;
    *(uint4*)&Bs0[hr * 40 + hc * 16] = b0a;
    *(uint4*)&Bs0[hr * 40 + hc * 16 + 8] = b0b;
    __syncthreads();
    bf16x8 af[2];
#pragma unroll
    for (int rf = 0; rf < 2; rf++)
      af[rf] = *(const bf16x8*)&As[(wv * 32 + rf * 16 + m) * 40 + q * 8];
#pragma unroll
    for (int nt = 0; nt < 8; nt++) {
      bf16x8 f1 = *(const bf16x8*)&Bs1[(nt * 16 + m) * 40 + q * 8];
      bf16x8 f0 = *(const bf16x8*)&Bs0[(nt * 16 + m) * 40 + q * 8];
      acc1[0][nt] = __builtin_amdgcn_mfma_f32_16x16x32_bf16(af[0], f1, acc1[0][nt], 0, 0, 0);
      acc1[1][nt] = __builtin_amdgcn_mfma_f32_16x16x32_bf16(af[1], f1, acc1[1][nt], 0, 0, 0);
      acc0[0][nt] = __builtin_amdgcn_mfma_f32_16x16x32_bf16(af[0], f0, acc0[0][nt], 0, 0, 0);
      acc0[1][nt] = __builtin_amdgcn_mfma_f32_16x16x32_bf16(af[1], f0, acc0[1][nt], 0, 0, 0);
    }
    __syncthreads();
  }
#pragma unroll
  for (int rf = 0; rf < 2; rf++) {
    const int rbase = row0 + wv * 32 + rf * 16 + q * 4;
    int mk[4];
#pragma unroll
    for (int r = 0; r < 4; r++) mk[r] = (rbase + r < NN) ? mask[rbase + r] : 0;
#pragma unroll
    for (int nt = 0; nt < 8; nt++) {
      const int gc = col0 + nt * 16 + m;
      const float bb1 = bias1[gc];
      const float bb0 = bias0[gc];
#pragma unroll
      for (int r = 0; r < 4; r++) {
        const int grr = rbase + r;
        if (grr < NN) {
          float v1 = fmaxf(acc1[rf][nt][r] + bb1, 0.0f);
          float v0 = fmaxf(acc0[rf][nt][r] + bb0, 0.0f);
          float o = mk[r] ? (0.8f * v1 + 0.2f * v0) : (0.8f * v0 + 0.2f * v1);
          xmb[grr * 256 + gc] = f2bf(o);
        }
      }
    }
  }
}

// ---------------- pull-mode aggregation: one wave per row; normalization fused (no deg pass)
__global__ __launch_bounds__(256) void aggregate_kernel(
    const int* __restrict__ start, const int* __restrict__ cnt,
    const uint2* __restrict__ colw,
    const unsigned short* __restrict__ xmb, unsigned short* __restrict__ aggb) {
  const int wave = threadIdx.x >> 6, lane = threadIdx.x & 63;
  const int row = blockIdx.x * 4 + wave;
  const int s = start[row];
  const int c = cnt[row];
  const int choff = lane * 4;
  f32x4 acc = (f32x4)(0.0f);
  float dsum = 0.0f;
  int i = 0;
  for (; i + 4 <= c; i += 4) {
    uint2 cw0 = colw[s + i], cw1 = colw[s + i + 1];
    uint2 cw2 = colw[s + i + 2], cw3 = colw[s + i + 3];
    const float w0 = __uint_as_float(cw0.y), w1 = __uint_as_float(cw1.y);
    const float w2 = __uint_as_float(cw2.y), w3 = __uint_as_float(cw3.y);
    uint2 u0 = *(const uint2*)(xmb + (int)cw0.x * 256 + choff);
    uint2 u1 = *(const uint2*)(xmb + (int)cw1.x * 256 + choff);
    uint2 u2 = *(const uint2*)(xmb + (int)cw2.x * 256 + choff);
    uint2 u3 = *(const uint2*)(xmb + (int)cw3.x * 256 + choff);
    dsum += (w0 + w1) + (w2 + w3);
    acc[0] = fmaf(w0, __uint_as_float(u0.x << 16), acc[0]);
    acc[1] = fmaf(w0, __uint_as_float(u0.x & 0xffff0000u), acc[1]);
    acc[2] = fmaf(w0, __uint_as_float(u0.y << 16), acc[2]);
    acc[3] = fmaf(w0, __uint_as_float(u0.y & 0xffff0000u), acc[3]);
    acc[0] = fmaf(w1, __uint_as_float(u1.x << 16), acc[0]);
    acc[1] = fmaf(w1, __uint_as_float(u1.x & 0xffff0000u), acc[1]);
    acc[2] = fmaf(w1, __uint_as_float(u1.y << 16), acc[2]);
    acc[3] = fmaf(w1, __uint_as_float(u1.y & 0xffff0000u), acc[3]);
    acc[0] = fmaf(w2, __uint_as_float(u2.x << 16), acc[0]);
    acc[1] = fmaf(w2, __uint_as_float(u2.x & 0xffff0000u), acc[1]);
    acc[2] = fmaf(w2, __uint_as_float(u2.y << 16), acc[2]);
    acc[3] = fmaf(w2, __uint_as_float(u2.y & 0xffff0000u), acc[3]);
    acc[0] = fmaf(w3, __uint_as_float(u3.x << 16), acc[0]);
    acc[1] = fmaf(w3, __uint_as_float(u3.x & 0xffff0000u), acc[1]);
    acc[2] = fmaf(w3, __uint_as_float(u3.y << 16), acc[2]);
    acc[3] = fmaf(w3, __uint_as_float(u3.y & 0xffff0000u), acc[3]);
  }
  for (; i < c; i++) {
    uint2 cw0 = colw[s + i];
    const float w0 = __uint_as_float(cw0.y);
    uint2 u0 = *(const uint2*)(xmb + (int)cw0.x * 256 + choff);
    dsum += w0;
    acc[0] = fmaf(w0, __uint_as_float(u0.x << 16), acc[0]);
    acc[1] = fmaf(w0, __uint_as_float(u0.x & 0xffff0000u), acc[1]);
    acc[2] = fmaf(w0, __uint_as_float(u0.y << 16), acc[2]);
    acc[3] = fmaf(w0, __uint_as_float(u0.y & 0xffff0000u), acc[3]);
  }
  float d = (dsum < 0.5f) ? dsum + 1.0f : dsum;
  const float inv = 1.0f / d;
  unsigned short o[4];
#pragma unroll
  for (int j = 0; j < 4; j++) o[j] = f2bf(acc[j] * inv);
  *(uint2*)(aggb + row * 256 + choff) = *(const uint2*)o;
}

// ---------------- per-channel sums for GraphNorm (reads bf16 agg)
__global__ __launch_bounds__(256) void stats_kernel(
    const unsigned short* __restrict__ aggb, float* __restrict__ S1, float* __restrict__ S2) {
  const int c = threadIdx.x;
  const int r0 = blockIdx.x * 200;
  float s1 = 0.0f, s2 = 0.0f;
  for (int r = 0; r < 200; r++) {
    float v = bfu2f(aggb[(r0 + r) * 256 + c]);
    s1 += v;
    s2 = fmaf(v, v, s2);
  }
  unsafeAtomicAdd(&S1[c], s1);
  unsafeAtomicAdd(&S2[c], s2);
}

__global__ void finalize_kernel(
    const float* __restrict__ S1, const float* __restrict__ S2,
    const float* __restrict__ gw, const float* __restrict__ gb,
    const float* __restrict__ ga,
    float* __restrict__ scale, float* __restrict__ shift) {
  const int c = threadIdx.x;
  const float inv_n = 1.0f / (float)NN;
  float mean = S1[c] * inv_n;
  float ex2 = S2[c] * inv_n;
  float am = ga[c] * mean;
  float var = ex2 - 2.0f * am * mean + am * am;
  float sc = gw[c] * rsqrtf(var + 1e-5f);
  scale[c] = sc;
  shift[c] = gb[c] - sc * am;
}

// ---------------- combine GEMM (128x128 tile): out = mix(mask, xc@Wc1+bc1, xc@Wc0+bc0)
__global__ __launch_bounds__(256, 2) void gemm_combine(
    const unsigned short* __restrict__ aggb,
    const float* __restrict__ scale, const float* __restrict__ shift,
    const float* __restrict__ X,
    const unsigned short* __restrict__ WT1, const unsigned short* __restrict__ WT0,
    const float* __restrict__ bias1, const float* __restrict__ bias0,
    const int* __restrict__ mask, float* __restrict__ out) {
  __shared__ __align__(16) unsigned short As[128 * 40];
  __shared__ __align__(16) unsigned short Bs1[128 * 40];
  __shared__ __align__(16) unsigned short Bs0[128 * 40];
  __shared__ float scL[256];
  __shared__ float shL[256];
  const int t = threadIdx.x;
  scL[t] = scale[t];
  shL[t] = shift[t];
  const int col0 = blockIdx.x * 128, row0 = blockIdx.y * 128;
  const int wv = t >> 6, lane = t & 63, m = lane & 15, q = lane >> 4;
  const int hr = t >> 1, hc = t & 1;
  f32x4 acc1[2][8], acc0[2][8];
#pragma unroll
  for (int rf = 0; rf < 2; rf++)
#pragma unroll
    for (int nt = 0; nt < 8; nt++) { acc1[rf][nt] = (f32x4)(0.0f); acc0[rf][nt] = (f32x4)(0.0f); }
  const int gr = row0 + hr;
  __syncthreads();  // scL/shL ready
  for (int k0 = 0; k0 < 512; k0 += 32) {
    unsigned short av[16];
#pragma unroll
    for (int i = 0; i < 16; i++) av[i] = 0;
    if (gr < NN) {
      if (k0 < 256) {
        const int c0 = k0 + hc * 16;
        uint4 ua = *(const uint4*)(aggb + gr * 256 + c0);
        uint4 ub = *(const uint4*)(aggb + gr * 256 + c0 + 8);
        const unsigned short* us = (const unsigned short*)&ua;
        const unsigned short* vs = (const unsigned short*)&ub;
#pragma unroll
        for (int i = 0; i < 8; i++) {
          av[i] = f2bf(fmaf(scL[c0 + i], bfu2f(us[i]), shL[c0 + i]));
          av[8 + i] = f2bf(fmaf(scL[c0 + 8 + i], bfu2f(vs[i]), shL[c0 + 8 + i]));
        }
      } else {
        const float* xp = X + gr * 256 + (k0 - 256) + hc * 16;
        f32x4 x0 = *(const f32x4*)(xp);
        f32x4 x1 = *(const f32x4*)(xp + 4);
        f32x4 x2 = *(const f32x4*)(xp + 8);
        f32x4 x3 = *(const f32x4*)(xp + 12);
#pragma unroll
        for (int i = 0; i < 4; i++) {
          av[i] = f2bf(x0[i]); av[4 + i] = f2bf(x1[i]);
          av[8 + i] = f2bf(x2[i]); av[12 + i] = f2bf(x3[i]);
        }
      }
    }
    *(uint4*)&As[hr * 40 + hc * 16] = ((const uint4*)av)[0];
    *(uint4*)&As[hr * 40 + hc * 16 + 8] = ((const uint4*)av)[1];
    const unsigned short* w1p = WT1 + (col0 + hr) * 512 + k0 + hc * 16;
    const unsigned short* w0p = WT0 + (col0 + hr) * 512 + k0 + hc * 16;
    uint4 b1a = *(const uint4*)w1p;
    uint4 b1b = *(const uint4*)(w1p + 8);
    uint4 b0a = *(const uint4*)w0p;
    uint4 b0b = *(const uint4*)(w0p + 8);
    *(uint4*)&Bs1[hr * 40 + hc * 16] = b1a;
    *(uint4*)&Bs1[hr * 40 + hc * 16 + 8] = b1b;
    *(uint4*)&Bs0[hr * 40 + hc * 16] = b0a;
    *(uint4*)&Bs0[hr * 40 + hc * 16 + 8] = b0b;
    __syncthreads();
    bf16x8 af[2];
#pragma unroll
    for (int rf = 0; rf < 2; rf++)
      af[rf] = *(const bf16x8*)&As[(wv * 32 + rf * 16 + m) * 40 + q * 8];
#pragma unroll
    for (int nt = 0; nt < 8; nt++) {
      bf16x8 f1 = *(const bf16x8*)&Bs1[(nt * 16 + m) * 40 + q * 8];
      bf16x8 f0 = *(const bf16x8*)&Bs0[(nt * 16 + m) * 40 + q * 8];
      acc1[0][nt] = __builtin_amdgcn_mfma_f32_16x16x32_bf16(af[0], f1, acc1[0][nt], 0, 0, 0);
      acc1[1][nt] = __builtin_amdgcn_mfma_f32_16x16x32_bf16(af[1], f1, acc1[1][nt], 0, 0, 0);
      acc0[0][nt] = __builtin_amdgcn_mfma_f32_16x16x32_bf16(af[0], f0, acc0[0][nt], 0, 0, 0);
      acc0[1][nt] = __builtin_amdgcn_mfma_f32_16x16x32_bf16(af[1], f0, acc0[1][nt], 0, 0, 0);
    }
    __syncthreads();
  }
#pragma unroll
  for (int rf = 0; rf < 2; rf++) {
    const int rbase = row0 + wv * 32 + rf * 16 + q * 4;
    int mk[4];
#pragma unroll
    for (int r = 0; r < 4; r++) mk[r] = (rbase + r < NN) ? mask[rbase + r] : 0;
#pragma unroll
    for (int nt = 0; nt < 8; nt++) {
      const int gc = col0 + nt * 16 + m;
      const float bb1 = bias1[gc];
      const float bb0 = bias0[gc];
#pragma unroll
      for (int r = 0; r < 4; r++) {
        const int grr = rbase + r;
        if (grr < NN) {
          float v1 = acc1[rf][nt][r] + bb1;
          float v0 = acc0[rf][nt][r] + bb0;
          float o = mk[r] ? (0.8f * v1 + 0.2f * v0) : (0.8f * v0 + 0.2f * v1);
          out[grr * 256 + gc] = o;
        }
      }
    }
  }
}

extern "C" void kernel_launch(void* const* d_in, const int* in_sizes, int n_in,
                              void* d_out, int out_size, void* d_ws, size_t ws_size,
                              hipStream_t stream) {
  (void)in_sizes; (void)n_in; (void)out_size; (void)ws_size;
  const float* x   = (const float*)d_in[0];
  const int*   ei  = (const int*)d_in[1];
  const int*   msk = (const int*)d_in[3];
  const float* ea  = (const float*)d_in[4];
  const float* Wt0 = (const float*)d_in[5];
  const float* bt0 = (const float*)d_in[6];
  const float* Wt1 = (const float*)d_in[7];
  const float* bt1 = (const float*)d_in[8];
  const float* Wc0 = (const float*)d_in[9];
  const float* bc0 = (const float*)d_in[10];
  const float* Wc1 = (const float*)d_in[11];
  const float* bc1 = (const float*)d_in[12];
  const float* gnw = (const float*)d_in[13];
  const float* gnb = (const float*)d_in[14];
  const float* gna = (const float*)d_in[15];
  const float* Wm1 = (const float*)d_in[16];
  const float* bm1 = (const float*)d_in[17];
  const float* Wm2 = (const float*)d_in[18];
  const float* bm2 = (const float*)d_in[19];

  // workspace layout (bytes), total ~62.6 MB:
  //   [0, 200704)              cnt i32[NNP]
  //   [200704, 401408)         start i32[NNP]
  //   [401408, 402432)         blockSum i32[256]
  //   [402432, 406528)         S1|S2|scale|shift f32[256] each
  //   [1048576, 4248576)       rank i32[NE]
  //   [4248576, 10648576)      colw uint2[NE]  (col,w interleaved)
  //   [10648576, 36248576)     xm bf16[NN*256]
  //   [36248576, 61848576)     agg bf16[NN*256]
  //   [61848576, 61979648)     WTt1 bf16[256*256]
  //   [61979648, 62110720)     WTt0 bf16[256*256]
  //   [62110720, 62372864)     WTc1 bf16[256*512]
  //   [62372864, 62635008)     WTc0 bf16[256*512]
  char* ws = (char*)d_ws;
  int* cnt      = (int*)ws;
  int* startA   = (int*)(ws + 200704);
  int* blockSum = (int*)(ws + 401408);
  float* S1     = (float*)(ws + 402432);
  float* S2     = (float*)(ws + 402432 + 1024);
  float* scaleP = (float*)(ws + 402432 + 2048);
  float* shiftP = (float*)(ws + 402432 + 3072);
  int* rankA    = (int*)(ws + 1048576);
  uint2* colw   = (uint2*)(ws + 4248576);
  unsigned short* xmb  = (unsigned short*)(ws + 10648576);
  unsigned short* aggb = (unsigned short*)(ws + 36248576);
  unsigned short* WTt1 = (unsigned short*)(ws + 61848576);
  unsigned short* WTt0 = (unsigned short*)(ws + 61979648);
  unsigned short* WTc1 = (unsigned short*)(ws + 62110720);
  unsigned short* WTc0 = (unsigned short*)(ws + 62372864);

  hipMemsetAsync(ws, 0, 406528, stream);  // cnt + stats

  transpose_w<<<dim3(8, 8), 256, 0, stream>>>(Wt1, WTt1, 256, 256);
  transpose_w<<<dim3(8, 8), 256, 0, stream>>>(Wt0, WTt0, 256, 256);
  transpose_w<<<dim3(16, 8), 256, 0, stream>>>(Wc1, WTc1, 512, 256);
  transpose_w<<<dim3(16, 8), 256, 0, stream>>>(Wc0, WTc0, 512, 256);

  count_kernel<<<3125, 256, 0, stream>>>(ei, cnt, rankA);
  scan1_kernel<<<196, 256, 0, stream>>>(cnt, blockSum);
  scan2_kernel<<<1, 256, 0, stream>>>(blockSum);
  scan3_kernel<<<196, 256, 0, stream>>>(cnt, blockSum, startA);
  mlp_fill_kernel<<<1563, 256, 0, stream>>>(ea, Wm1, bm1, Wm2, bm2, ei, startA, rankA, colw);
  gemm_transform<<<dim3(2, 391), 256, 0, stream>>>(x, WTt1, WTt0, bt1, bt0, msk, xmb);
  aggregate_kernel<<<12500, 256, 0, stream>>>(startA, cnt, colw, xmb, aggb);
  stats_kernel<<<250, 256, 0, stream>>>(aggb, S1, S2);
  finalize_kernel<<<1, 256, 0, stream>>>(S1, S2, gnw, gnb, gna, scaleP, shiftP);
  gemm_combine<<<dim3(2, 391), 256, 0, stream>>>(aggb, scaleP, shiftP, x, WTc1, WTc0,
                                                 bc1, bc0, msk, (float*)d_out);
}

// Round 7
// 438.827 us; speedup vs baseline: 1.2262x; 1.2262x over previous
//
#include <hip/hip_runtime.h>

#define NN 50000
#define NE 800000
#define NNP 50176  // 196*256

typedef __attribute__((ext_vector_type(4))) float f32x4;
typedef __bf16 bf16x8 __attribute__((ext_vector_type(8)));

__device__ __forceinline__ float bfu2f(unsigned short u) {
  return __uint_as_float(((unsigned)u) << 16);
}
__device__ __forceinline__ unsigned short f2bf(float f) {
  unsigned u = __float_as_uint(f);
  u += 0x7fffu + ((u >> 16) & 1u);
  return (unsigned short)(u >> 16);
}

// ---------------- weight prep: W[K][N] fp32 -> WT[N][K] bf16 (run once per launch)
__global__ __launch_bounds__(256) void transpose_w(
    const float* __restrict__ W, unsigned short* __restrict__ WT, int K, int N) {
  __shared__ unsigned short T[32 * 40];
  const int t = threadIdx.x;
  const int k0 = blockIdx.x * 32, n0 = blockIdx.y * 32;
  const int kk = t >> 3, nn = (t & 7) * 4;
  f32x4 v = *(const f32x4*)(W + (k0 + kk) * N + n0 + nn);
#pragma unroll
  for (int i = 0; i < 4; i++) T[(nn + i) * 40 + kk] = f2bf(v[i]);
  __syncthreads();
  const int nn2 = t >> 3, kk2 = (t & 7) * 4;
  unsigned short o[4];
#pragma unroll
  for (int i = 0; i < 4; i++) o[i] = T[nn2 * 40 + kk2 + i];
  *(uint2*)(WT + (n0 + nn2) * K + k0 + kk2) = *(const uint2*)o;
}

// ---------------- count: rank[e] = old cnt[row]++  (the only atomic pass)
__global__ __launch_bounds__(256) void count_kernel(
    const int* __restrict__ ei, int* __restrict__ cnt, int* __restrict__ rank) {
  const int e = blockIdx.x * 256 + threadIdx.x;
  if (e >= NE) return;
  rank[e] = atomicAdd(&cnt[ei[e]], 1);
}

// ---------------- CSR build: hierarchical exclusive scan of cnt
__global__ __launch_bounds__(256) void scan1_kernel(const int* __restrict__ cnt,
                                                    int* __restrict__ blockSum) {
  __shared__ int sd[256];
  const int t = threadIdx.x;
  sd[t] = cnt[blockIdx.x * 256 + t];
  __syncthreads();
  for (int off = 128; off > 0; off >>= 1) {
    if (t < off) sd[t] += sd[t + off];
    __syncthreads();
  }
  if (t == 0) blockSum[blockIdx.x] = sd[0];
}

__global__ __launch_bounds__(256) void scan2_kernel(int* __restrict__ blockSum) {
  __shared__ int sd[256];
  const int t = threadIdx.x;
  int v = (t < 196) ? blockSum[t] : 0;
  sd[t] = v;
  __syncthreads();
  for (int off = 1; off < 256; off <<= 1) {
    int y = (t >= off) ? sd[t - off] : 0;
    __syncthreads();
    sd[t] += y;
    __syncthreads();
  }
  int ex = (t == 0) ? 0 : sd[t - 1];
  __syncthreads();
  if (t < 196) blockSum[t] = ex;
}

__global__ __launch_bounds__(256) void scan3_kernel(
    const int* __restrict__ cnt, const int* __restrict__ blockSum,
    int* __restrict__ start) {
  __shared__ int sd[256];
  const int t = threadIdx.x;
  const int row = blockIdx.x * 256 + t;
  const int c = cnt[row];
  sd[t] = c;
  __syncthreads();
  for (int off = 1; off < 256; off <<= 1) {
    int y = (t >= off) ? sd[t - off] : 0;
    __syncthreads();
    sd[t] += y;
    __syncthreads();
  }
  start[row] = blockSum[blockIdx.x] + sd[t] - c;  // exclusive
}

// ---------------- fused edge MLP + CSR fill (1 edge/thread, lean registers, no atomics)
__device__ __forceinline__ void mlp4(float a0, float a1, float a2, float a3,
                                     const f32x4* __restrict__ w,
                                     f32x4& h0, f32x4& h1, f32x4& h2, f32x4& h3,
                                     f32x4& h4, f32x4& h5, f32x4& h6, f32x4& h7) {
  h0 += w[0] * a0;  h1 += w[1] * a0;  h2 += w[2] * a0;  h3 += w[3] * a0;
  h4 += w[4] * a0;  h5 += w[5] * a0;  h6 += w[6] * a0;  h7 += w[7] * a0;
  h0 += w[8] * a1;  h1 += w[9] * a1;  h2 += w[10] * a1; h3 += w[11] * a1;
  h4 += w[12] * a1; h5 += w[13] * a1; h6 += w[14] * a1; h7 += w[15] * a1;
  h0 += w[16] * a2; h1 += w[17] * a2; h2 += w[18] * a2; h3 += w[19] * a2;
  h4 += w[20] * a2; h5 += w[21] * a2; h6 += w[22] * a2; h7 += w[23] * a2;
  h0 += w[24] * a3; h1 += w[25] * a3; h2 += w[26] * a3; h3 += w[27] * a3;
  h4 += w[28] * a3; h5 += w[29] * a3; h6 += w[30] * a3; h7 += w[31] * a3;
}

__device__ __forceinline__ float rdot(f32x4 h, f32x4 w) {
  float s = fmaxf(h[0], 0.0f) * w[0];
  s = fmaf(fmaxf(h[1], 0.0f), w[1], s);
  s = fmaf(fmaxf(h[2], 0.0f), w[2], s);
  s = fmaf(fmaxf(h[3], 0.0f), w[3], s);
  return s;
}

__global__ __launch_bounds__(256) void mlp_fill_kernel(
    const float* __restrict__ ea,
    const float* __restrict__ Wm1, const float* __restrict__ bm1,
    const float* __restrict__ Wm2, const float* __restrict__ bm2,
    const int* __restrict__ ei, const int* __restrict__ start,
    const int* __restrict__ rank, uint2* __restrict__ colw) {
  __shared__ __align__(16) float w1[512];
  __shared__ __align__(16) float b1[32];
  __shared__ __align__(16) float w2[32];
  __shared__ float b2s[1];
  const int t = threadIdx.x;
  w1[t] = Wm1[t];
  w1[t + 256] = Wm1[t + 256];
  if (t < 32) { b1[t] = bm1[t]; w2[t] = Wm2[t]; }
  if (t == 0) b2s[0] = bm2[0];
  __syncthreads();
  const int e = blockIdx.x * 256 + t;
  if (e >= NE) return;
  f32x4 r0 = *(const f32x4*)(ea + e * 16);
  f32x4 r1 = *(const f32x4*)(ea + e * 16 + 4);
  f32x4 r2 = *(const f32x4*)(ea + e * 16 + 8);
  f32x4 r3 = *(const f32x4*)(ea + e * 16 + 12);
  const f32x4* bv = (const f32x4*)b1;
  f32x4 h0 = bv[0], h1 = bv[1], h2 = bv[2], h3 = bv[3];
  f32x4 h4 = bv[4], h5 = bv[5], h6 = bv[6], h7 = bv[7];
  const f32x4* wv = (const f32x4*)w1;
  mlp4(r0[0], r0[1], r0[2], r0[3], wv, h0, h1, h2, h3, h4, h5, h6, h7);
  mlp4(r1[0], r1[1], r1[2], r1[3], wv + 32, h0, h1, h2, h3, h4, h5, h6, h7);
  mlp4(r2[0], r2[1], r2[2], r2[3], wv + 64, h0, h1, h2, h3, h4, h5, h6, h7);
  mlp4(r3[0], r3[1], r3[2], r3[3], wv + 96, h0, h1, h2, h3, h4, h5, h6, h7);
  const f32x4* w2v = (const f32x4*)w2;
  float s = b2s[0];
  s += rdot(h0, w2v[0]) + rdot(h1, w2v[1]) + rdot(h2, w2v[2]) + rdot(h3, w2v[3]);
  s += rdot(h4, w2v[4]) + rdot(h5, w2v[5]) + rdot(h6, w2v[6]) + rdot(h7, w2v[7]);
  const float sp = (s > 0.0f) ? (s + log1pf(expf(-s))) : log1pf(expf(s));
  uint2 p;
  p.x = (unsigned)ei[NE + e];
  p.y = __float_as_uint(sp);
  colw[start[ei[e]] + rank[e]] = p;
}

// ---------------- transform GEMM (128x128 tile): xm = mix(mask, relu(x@Wt1+bt1), relu(x@Wt0+bt0))
__global__ __launch_bounds__(256, 2) void gemm_transform(
    const float* __restrict__ X,
    const unsigned short* __restrict__ WT1, const unsigned short* __restrict__ WT0,
    const float* __restrict__ bias1, const float* __restrict__ bias0,
    const int* __restrict__ mask, unsigned short* __restrict__ xmb) {
  __shared__ __align__(16) unsigned short As[128 * 40];
  __shared__ __align__(16) unsigned short Bs1[128 * 40];
  __shared__ __align__(16) unsigned short Bs0[128 * 40];
  const int t = threadIdx.x;
  const int col0 = blockIdx.x * 128, row0 = blockIdx.y * 128;
  const int wv = t >> 6, lane = t & 63, m = lane & 15, q = lane >> 4;
  const int hr = t >> 1, hc = t & 1;  // staging: row/n index 0..127, k-half 0/1
  f32x4 acc1[2][8], acc0[2][8];
#pragma unroll
  for (int rf = 0; rf < 2; rf++)
#pragma unroll
    for (int nt = 0; nt < 8; nt++) { acc1[rf][nt] = (f32x4)(0.0f); acc0[rf][nt] = (f32x4)(0.0f); }
  const int gr = row0 + hr;
  for (int k0 = 0; k0 < 256; k0 += 32) {
    unsigned short av[16];
    if (gr < NN) {
      const float* xp = X + gr * 256 + k0 + hc * 16;
      f32x4 x0 = *(const f32x4*)(xp);
      f32x4 x1 = *(const f32x4*)(xp + 4);
      f32x4 x2 = *(const f32x4*)(xp + 8);
      f32x4 x3 = *(const f32x4*)(xp + 12);
#pragma unroll
      for (int i = 0; i < 4; i++) {
        av[i] = f2bf(x0[i]); av[4 + i] = f2bf(x1[i]);
        av[8 + i] = f2bf(x2[i]); av[12 + i] = f2bf(x3[i]);
      }
    } else {
#pragma unroll
      for (int i = 0; i < 16; i++) av[i] = 0;
    }
    *(uint4*)&As[hr * 40 + hc * 16] = ((const uint4*)av)[0];
    *(uint4*)&As[hr * 40 + hc * 16 + 8] = ((const uint4*)av)[1];
    const unsigned short* w1p = WT1 + (col0 + hr) * 256 + k0 + hc * 16;
    const unsigned short* w0p = WT0 + (col0 + hr) * 256 + k0 + hc * 16;
    uint4 b1a = *(const uint4*)w1p;
    uint4 b1b = *(const uint4*)(w1p + 8);
    uint4 b0a = *(const uint4*)w0p;
    uint4 b0b = *(const uint4*)(w0p + 8);
    *(uint4*)&Bs1[hr * 40 + hc * 16] = b1a;
    *(uint4*)&Bs1[hr * 40 + hc * 16 + 8] = b1b;
    *(uint4*)&Bs0[hr * 40 + hc * 16] = b0a;
    *(uint4*)&Bs0[hr * 40 + hc * 16 + 8] = b0b;
    __syncthreads();
    bf16x8 af[2];
#pragma unroll
    for (int rf = 0; rf < 2; rf++)
      af[rf] = *(const bf16x8*)&As[(wv * 32 + rf * 16 + m) * 40 + q * 8];
#pragma unroll
    for (int nt = 0; nt < 8; nt++) {
      bf16x8 f1 = *(const bf16x8*)&Bs1[(nt * 16 + m) * 40 + q * 8];
      bf16x8 f0 = *(const bf16x8*)&Bs0[(nt * 16 + m) * 40 + q * 8];
      acc1[0][nt] = __builtin_amdgcn_mfma_f32_16x16x32_bf16(af[0], f1, acc1[0][nt], 0, 0, 0);
      acc1[1][nt] = __builtin_amdgcn_mfma_f32_16x16x32_bf16(af[1], f1, acc1[1][nt], 0, 0, 0);
      acc0[0][nt] = __builtin_amdgcn_mfma_f32_16x16x32_bf16(af[0], f0, acc0[0][nt], 0, 0, 0);
      acc0[1][nt] = __builtin_amdgcn_mfma_f32_16x16x32_bf16(af[1], f0, acc0[1][nt], 0, 0, 0);
    }
    __syncthreads();
  }
#pragma unroll
  for (int rf = 0; rf < 2; rf++) {
    const int rbase = row0 + wv * 32 + rf * 16 + q * 4;
    int mk[4];
#pragma unroll
    for (int r = 0; r < 4; r++) mk[r] = (rbase + r < NN) ? mask[rbase + r] : 0;
#pragma unroll
    for (int nt = 0; nt < 8; nt++) {
      const int gc = col0 + nt * 16 + m;
      const float bb1 = bias1[gc];
      const float bb0 = bias0[gc];
#pragma unroll
      for (int r = 0; r < 4; r++) {
        const int grr = rbase + r;
        if (grr < NN) {
          float v1 = fmaxf(acc1[rf][nt][r] + bb1, 0.0f);
          float v0 = fmaxf(acc0[rf][nt][r] + bb0, 0.0f);
          float o = mk[r] ? (0.8f * v1 + 0.2f * v0) : (0.8f * v0 + 0.2f * v1);
          xmb[grr * 256 + gc] = f2bf(o);
        }
      }
    }
  }
}

// ---------------- pull-mode aggregation: one wave per row; normalization fused (no deg pass)
__global__ __launch_bounds__(256) void aggregate_kernel(
    const int* __restrict__ start, const int* __restrict__ cnt,
    const uint2* __restrict__ colw,
    const unsigned short* __restrict__ xmb, unsigned short* __restrict__ aggb) {
  const int wave = threadIdx.x >> 6, lane = threadIdx.x & 63;
  const int row = blockIdx.x * 4 + wave;
  const int s = start[row];
  const int c = cnt[row];
  const int choff = lane * 4;
  f32x4 acc = (f32x4)(0.0f);
  float dsum = 0.0f;
  int i = 0;
  for (; i + 4 <= c; i += 4) {
    uint2 cw0 = colw[s + i], cw1 = colw[s + i + 1];
    uint2 cw2 = colw[s + i + 2], cw3 = colw[s + i + 3];
    const float w0 = __uint_as_float(cw0.y), w1 = __uint_as_float(cw1.y);
    const float w2 = __uint_as_float(cw2.y), w3 = __uint_as_float(cw3.y);
    uint2 u0 = *(const uint2*)(xmb + (int)cw0.x * 256 + choff);
    uint2 u1 = *(const uint2*)(xmb + (int)cw1.x * 256 + choff);
    uint2 u2 = *(const uint2*)(xmb + (int)cw2.x * 256 + choff);
    uint2 u3 = *(const uint2*)(xmb + (int)cw3.x * 256 + choff);
    dsum += (w0 + w1) + (w2 + w3);
    acc[0] = fmaf(w0, __uint_as_float(u0.x << 16), acc[0]);
    acc[1] = fmaf(w0, __uint_as_float(u0.x & 0xffff0000u), acc[1]);
    acc[2] = fmaf(w0, __uint_as_float(u0.y << 16), acc[2]);
    acc[3] = fmaf(w0, __uint_as_float(u0.y & 0xffff0000u), acc[3]);
    acc[0] = fmaf(w1, __uint_as_float(u1.x << 16), acc[0]);
    acc[1] = fmaf(w1, __uint_as_float(u1.x & 0xffff0000u), acc[1]);
    acc[2] = fmaf(w1, __uint_as_float(u1.y << 16), acc[2]);
    acc[3] = fmaf(w1, __uint_as_float(u1.y & 0xffff0000u), acc[3]);
    acc[0] = fmaf(w2, __uint_as_float(u2.x << 16), acc[0]);
    acc[1] = fmaf(w2, __uint_as_float(u2.x & 0xffff0000u), acc[1]);
    acc[2] = fmaf(w2, __uint_as_float(u2.y << 16), acc[2]);
    acc[3] = fmaf(w2, __uint_as_float(u2.y & 0xffff0000u), acc[3]);
    acc[0] = fmaf(w3, __uint_as_float(u3.x << 16), acc[0]);
    acc[1] = fmaf(w3, __uint_as_float(u3.x & 0xffff0000u), acc[1]);
    acc[2] = fmaf(w3, __uint_as_float(u3.y << 16), acc[2]);
    acc[3] = fmaf(w3, __uint_as_float(u3.y & 0xffff0000u), acc[3]);
  }
  for (; i < c; i++) {
    uint2 cw0 = colw[s + i];
    const float w0 = __uint_as_float(cw0.y);
    uint2 u0 = *(const uint2*)(xmb + (int)cw0.x * 256 + choff);
    dsum += w0;
    acc[0] = fmaf(w0, __uint_as_float(u0.x << 16), acc[0]);
    acc[1] = fmaf(w0, __uint_as_float(u0.x & 0xffff0000u), acc[1]);
    acc[2] = fmaf(w0, __uint_as_float(u0.y << 16), acc[2]);
    acc[3] = fmaf(w0, __uint_as_float(u0.y & 0xffff0000u), acc[3]);
  }
  float d = (dsum < 0.5f) ? dsum + 1.0f : dsum;
  const float inv = 1.0f / d;
  unsigned short o[4];
#pragma unroll
  for (int j = 0; j < 4; j++) o[j] = f2bf(acc[j] * inv);
  *(uint2*)(aggb + row * 256 + choff) = *(const uint2*)o;
}

// ---------------- per-channel sums for GraphNorm (reads bf16 agg)
__global__ __launch_bounds__(256) void stats_kernel(
    const unsigned short* __restrict__ aggb, float* __restrict__ S1, float* __restrict__ S2) {
  const int c = threadIdx.x;
  const int r0 = blockIdx.x * 200;
  float s1 = 0.0f, s2 = 0.0f;
  for (int r = 0; r < 200; r++) {
    float v = bfu2f(aggb[(r0 + r) * 256 + c]);
    s1 += v;
    s2 = fmaf(v, v, s2);
  }
  unsafeAtomicAdd(&S1[c], s1);
  unsafeAtomicAdd(&S2[c], s2);
}

__global__ void finalize_kernel(
    const float* __restrict__ S1, const float* __restrict__ S2,
    const float* __restrict__ gw, const float* __restrict__ gb,
    const float* __restrict__ ga,
    float* __restrict__ scale, float* __restrict__ shift) {
  const int c = threadIdx.x;
  const float inv_n = 1.0f / (float)NN;
  float mean = S1[c] * inv_n;
  float ex2 = S2[c] * inv_n;
  float am = ga[c] * mean;
  float var = ex2 - 2.0f * am * mean + am * am;
  float sc = gw[c] * rsqrtf(var + 1e-5f);
  scale[c] = sc;
  shift[c] = gb[c] - sc * am;
}

// ---------------- combine GEMM (128x128 tile): out = mix(mask, xc@Wc1+bc1, xc@Wc0+bc0)
__global__ __launch_bounds__(256, 2) void gemm_combine(
    const unsigned short* __restrict__ aggb,
    const float* __restrict__ scale, const float* __restrict__ shift,
    const float* __restrict__ X,
    const unsigned short* __restrict__ WT1, const unsigned short* __restrict__ WT0,
    const float* __restrict__ bias1, const float* __restrict__ bias0,
    const int* __restrict__ mask, float* __restrict__ out) {
  __shared__ __align__(16) unsigned short As[128 * 40];
  __shared__ __align__(16) unsigned short Bs1[128 * 40];
  __shared__ __align__(16) unsigned short Bs0[128 * 40];
  __shared__ float scL[256];
  __shared__ float shL[256];
  const int t = threadIdx.x;
  scL[t] = scale[t];
  shL[t] = shift[t];
  const int col0 = blockIdx.x * 128, row0 = blockIdx.y * 128;
  const int wv = t >> 6, lane = t & 63, m = lane & 15, q = lane >> 4;
  const int hr = t >> 1, hc = t & 1;
  f32x4 acc1[2][8], acc0[2][8];
#pragma unroll
  for (int rf = 0; rf < 2; rf++)
#pragma unroll
    for (int nt = 0; nt < 8; nt++) { acc1[rf][nt] = (f32x4)(0.0f); acc0[rf][nt] = (f32x4)(0.0f); }
  const int gr = row0 + hr;
  __syncthreads();  // scL/shL ready
  for (int k0 = 0; k0 < 512; k0 += 32) {
    unsigned short av[16];
#pragma unroll
    for (int i = 0; i < 16; i++) av[i] = 0;
    if (gr < NN) {
      if (k0 < 256) {
        const int c0 = k0 + hc * 16;
        uint4 ua = *(const uint4*)(aggb + gr * 256 + c0);
        uint4 ub = *(const uint4*)(aggb + gr * 256 + c0 + 8);
        const unsigned short* us = (const unsigned short*)&ua;
        const unsigned short* vs = (const unsigned short*)&ub;
#pragma unroll
        for (int i = 0; i < 8; i++) {
          av[i] = f2bf(fmaf(scL[c0 + i], bfu2f(us[i]), shL[c0 + i]));
          av[8 + i] = f2bf(fmaf(scL[c0 + 8 + i], bfu2f(vs[i]), shL[c0 + 8 + i]));
        }
      } else {
        const float* xp = X + gr * 256 + (k0 - 256) + hc * 16;
        f32x4 x0 = *(const f32x4*)(xp);
        f32x4 x1 = *(const f32x4*)(xp + 4);
        f32x4 x2 = *(const f32x4*)(xp + 8);
        f32x4 x3 = *(const f32x4*)(xp + 12);
#pragma unroll
        for (int i = 0; i < 4; i++) {
          av[i] = f2bf(x0[i]); av[4 + i] = f2bf(x1[i]);
          av[8 + i] = f2bf(x2[i]); av[12 + i] = f2bf(x3[i]);
        }
      }
    }
    *(uint4*)&As[hr * 40 + hc * 16] = ((const uint4*)av)[0];
    *(uint4*)&As[hr * 40 + hc * 16 + 8] = ((const uint4*)av)[1];
    const unsigned short* w1p = WT1 + (col0 + hr) * 512 + k0 + hc * 16;
    const unsigned short* w0p = WT0 + (col0 + hr) * 512 + k0 + hc * 16;
    uint4 b1a = *(const uint4*)w1p;
    uint4 b1b = *(const uint4*)(w1p + 8);
    uint4 b0a = *(const uint4*)w0p;
    uint4 b0b = *(const uint4*)(w0p + 8);
    *(uint4*)&Bs1[hr * 40 + hc * 16] = b1a;
    *(uint4*)&Bs1[hr * 40 + hc * 16 + 8] = b1b;
    *(uint4*)&Bs0[hr * 40 + hc * 16] = b0a;
    *(uint4*)&Bs0[hr * 40 + hc * 16 + 8] = b0b;
    __syncthreads();
    bf16x8 af[2];
#pragma unroll
    for (int rf = 0; rf < 2; rf++)
      af[rf] = *(const bf16x8*)&As[(wv * 32 + rf * 16 + m) * 40 + q * 8];
#pragma unroll
    for (int nt = 0; nt < 8; nt++) {
      bf16x8 f1 = *(const bf16x8*)&Bs1[(nt * 16 + m) * 40 + q * 8];
      bf16x8 f0 = *(const bf16x8*)&Bs0[(nt * 16 + m) * 40 + q * 8];
      acc1[0][nt] = __builtin_amdgcn_mfma_f32_16x16x32_bf16(af[0], f1, acc1[0][nt], 0, 0, 0);
      acc1[1][nt] = __builtin_amdgcn_mfma_f32_16x16x32_bf16(af[1], f1, acc1[1][nt], 0, 0, 0);
      acc0[0][nt] = __builtin_amdgcn_mfma_f32_16x16x32_bf16(af[0], f0, acc0[0][nt], 0, 0, 0);
      acc0[1][nt] = __builtin_amdgcn_mfma_f32_16x16x32_bf16(af[1], f0, acc0[1][nt], 0, 0, 0);
    }
    __syncthreads();
  }
#pragma unroll
  for (int rf = 0; rf < 2; rf++) {
    const int rbase = row0 + wv * 32 + rf * 16 + q * 4;
    int mk[4];
#pragma unroll
    for (int r = 0; r < 4; r++) mk[r] = (rbase + r < NN) ? mask[rbase + r] : 0;
#pragma unroll
    for (int nt = 0; nt < 8; nt++) {
      const int gc = col0 + nt * 16 + m;
      const float bb1 = bias1[gc];
      const float bb0 = bias0[gc];
#pragma unroll
      for (int r = 0; r < 4; r++) {
        const int grr = rbase + r;
        if (grr < NN) {
          float v1 = acc1[rf][nt][r] + bb1;
          float v0 = acc0[rf][nt][r] + bb0;
          float o = mk[r] ? (0.8f * v1 + 0.2f * v0) : (0.8f * v0 + 0.2f * v1);
          out[grr * 256 + gc] = o;
        }
      }
    }
  }
}

extern "C" void kernel_launch(void* const* d_in, const int* in_sizes, int n_in,
                              void* d_out, int out_size, void* d_ws, size_t ws_size,
                              hipStream_t stream) {
  (void)in_sizes; (void)n_in; (void)out_size; (void)ws_size;
  const float* x   = (const float*)d_in[0];
  const int*   ei  = (const int*)d_in[1];
  const int*   msk = (const int*)d_in[3];
  const float* ea  = (const float*)d_in[4];
  const float* Wt0 = (const float*)d_in[5];
  const float* bt0 = (const float*)d_in[6];
  const float* Wt1 = (const float*)d_in[7];
  const float* bt1 = (const float*)d_in[8];
  const float* Wc0 = (const float*)d_in[9];
  const float* bc0 = (const float*)d_in[10];
  const float* Wc1 = (const float*)d_in[11];
  const float* bc1 = (const float*)d_in[12];
  const float* gnw = (const float*)d_in[13];
  const float* gnb = (const float*)d_in[14];
  const float* gna = (const float*)d_in[15];
  const float* Wm1 = (const float*)d_in[16];
  const float* bm1 = (const float*)d_in[17];
  const float* Wm2 = (const float*)d_in[18];
  const float* bm2 = (const float*)d_in[19];

  // workspace layout (bytes), total ~62.6 MB:
  //   [0, 200704)              cnt i32[NNP]
  //   [200704, 401408)         start i32[NNP]
  //   [401408, 402432)         blockSum i32[256]
  //   [402432, 406528)         S1|S2|scale|shift f32[256] each
  //   [1048576, 4248576)       rank i32[NE]
  //   [4248576, 10648576)      colw uint2[NE]  (col,w interleaved)
  //   [10648576, 36248576)     xm bf16[NN*256]
  //   [36248576, 61848576)     agg bf16[NN*256]
  //   [61848576, 61979648)     WTt1 bf16[256*256]
  //   [61979648, 62110720)     WTt0 bf16[256*256]
  //   [62110720, 62372864)     WTc1 bf16[256*512]
  //   [62372864, 62635008)     WTc0 bf16[256*512]
  char* ws = (char*)d_ws;
  int* cnt      = (int*)ws;
  int* startA   = (int*)(ws + 200704);
  int* blockSum = (int*)(ws + 401408);
  float* S1     = (float*)(ws + 402432);
  float* S2     = (float*)(ws + 402432 + 1024);
  float* scaleP = (float*)(ws + 402432 + 2048);
  float* shiftP = (float*)(ws + 402432 + 3072);
  int* rankA    = (int*)(ws + 1048576);
  uint2* colw   = (uint2*)(ws + 4248576);
  unsigned short* xmb  = (unsigned short*)(ws + 10648576);
  unsigned short* aggb = (unsigned short*)(ws + 36248576);
  unsigned short* WTt1 = (unsigned short*)(ws + 61848576);
  unsigned short* WTt0 = (unsigned short*)(ws + 61979648);
  unsigned short* WTc1 = (unsigned short*)(ws + 62110720);
  unsigned short* WTc0 = (unsigned short*)(ws + 62372864);

  hipMemsetAsync(ws, 0, 406528, stream);  // cnt + stats

  transpose_w<<<dim3(8, 8), 256, 0, stream>>>(Wt1, WTt1, 256, 256);
  transpose_w<<<dim3(8, 8), 256, 0, stream>>>(Wt0, WTt0, 256, 256);
  transpose_w<<<dim3(16, 8), 256, 0, stream>>>(Wc1, WTc1, 512, 256);
  transpose_w<<<dim3(16, 8), 256, 0, stream>>>(Wc0, WTc0, 512, 256);

  count_kernel<<<3125, 256, 0, stream>>>(ei, cnt, rankA);
  scan1_kernel<<<196, 256, 0, stream>>>(cnt, blockSum);
  scan2_kernel<<<1, 256, 0, stream>>>(blockSum);
  scan3_kernel<<<196, 256, 0, stream>>>(cnt, blockSum, startA);
  mlp_fill_kernel<<<3125, 256, 0, stream>>>(ea, Wm1, bm1, Wm2, bm2, ei, startA, rankA, colw);
  gemm_transform<<<dim3(2, 391), 256, 0, stream>>>(x, WTt1, WTt0, bt1, bt0, msk, xmb);
  aggregate_kernel<<<12500, 256, 0, stream>>>(startA, cnt, colw, xmb, aggb);
  stats_kernel<<<250, 256, 0, stream>>>(aggb, S1, S2);
  finalize_kernel<<<1, 256, 0, stream>>>(S1, S2, gnw, gnb, gna, scaleP, shiftP);
  gemm_combine<<<dim3(2, 391), 256, 0, stream>>>(aggb, scaleP, shiftP, x, WTc1, WTc0,
                                                 bc1, bc0, msk, (float*)d_out);
}